// Round 14
// baseline (624.830 us; speedup 1.0000x reference)
//
#include <hip/hip_runtime.h>
#include <hip/hip_bf16.h>

#define N_NODES 100000
#define N_EDGES 3200000
#define F_IN    128
#define H1F     64
#define H2F     32
#define NCLS    32
#define NTILES (N_NODES / 16)                                   // 6250 exact
#define NCNT   (N_EDGES / 4 / 256)                              // 3125 count blocks
#define XPAD 132                                                // 128+4 shorts: LDS de-alias
#define SLOTS 80                                                // fixed CSR row stride
#define OVCAP 65536                                             // overflow list capacity

typedef __attribute__((ext_vector_type(8))) short bf16x8;
typedef __attribute__((ext_vector_type(4))) float f32x4;

static __device__ __forceinline__ float b2f(__hip_bfloat16 v) {
    return __bfloat162float(v);
}
static __device__ __forceinline__ float us2f(unsigned short u) {
    return __uint_as_float(((unsigned)u) << 16);
}
static __device__ __forceinline__ unsigned short f2us(float f) {
    __hip_bfloat16 h = __float2bfloat16(f);
    return *(unsigned short*)&h;
}
static __device__ __forceinline__ float ld(const void* p, size_t i, int isbf) {
    return isbf ? b2f(((const __hip_bfloat16*)p)[i]) : ((const float*)p)[i];
}
static __device__ __forceinline__ float dinvf(int dg) {
    return rsqrtf((float)dg + 1.0f);                   // +1 self-loop
}

// flags[0] = edge_index is int64 ; flags[1] = float tensors are bf16

__global__ void k_detect(const void* xbuf, const void* eibuf, int* flags) {
    if (threadIdx.x != 0 || blockIdx.x != 0) return;
    const unsigned* ew = (const unsigned*)eibuf;
    int z = 0;
    for (int k = 0; k < 256; ++k) z += (ew[2 * k + 1] == 0u) ? 1 : 0;
    flags[0] = (z >= 200) ? 1 : 0;
    const unsigned* xw = (const unsigned*)xbuf;
    int inr = 0;
    for (int k = 0; k < 256; ++k) {
        unsigned fb = (xw[k] & 0xFFFFu) << 16;
        float a = fabsf(__uint_as_float(fb));
        inr += (a >= 1e-4f && a <= 20.0f) ? 1 : 0;
    }
    flags[1] = (inr >= 160) ? 1 : 0;
}

// ---------- pack W1 into MFMA B-fragment order ----------
__global__ void k_packW1(const unsigned short* __restrict__ W1,
                         unsigned short* __restrict__ W1p) {
    int t = blockIdx.x * blockDim.x + threadIdx.x;      // 8192 threads
    if (t >= F_IN * H1F) return;
    int j    = t & 7;
    int lane = (t >> 3) & 63;
    int fg   = (t >> 9) & 3;
    int kc   = t >> 11;
    int quad = lane >> 4, col = lane & 15;
    W1p[t] = W1[(kc * 32 + quad * 8 + j) * H1F + fg * 16 + col];
}

// ---------------- FUSED front-end ----------------
// blk%3==0 -> histogram + DIRECT fixed-slot CSR scatter (3125 blocks)
// else     -> gemm1 MFMA tile block (6250 blocks)
// Interleave keeps both types co-resident: MFMA/LDS work hides atomic+store latency.
__global__ void __launch_bounds__(256)
k_front(const void* __restrict__ x, const void* __restrict__ W1,
        const unsigned short* __restrict__ W1p, const int* __restrict__ ei,
        int* __restrict__ deg, int* __restrict__ csrF,
        int* __restrict__ novf, int2* __restrict__ ov,
        unsigned short* __restrict__ h1, const int* __restrict__ flags) {
    __shared__ unsigned short w1s[F_IN * H1F];          // 16 KB
    __shared__ unsigned short xs[16 * XPAD];            // 4.2 KB
    int blk = blockIdx.x, tid = threadIdx.x;

    if (blk % 3 == 0) {
        // -------- histogram + direct scatter --------
        int t = (blk / 3) * 256 + tid;
        int e0 = t * 4;
        if (e0 >= N_EDGES) return;
        int s[4], d[4];
        if (flags[0]) {
            const int4* ps = (const int4*)(ei + 2 * (size_t)e0);
            int4 a = ps[0], b = ps[1];
            s[0] = a.x; s[1] = a.z; s[2] = b.x; s[3] = b.z;
            const int4* pd = (const int4*)(ei + 2 * (size_t)(N_EDGES + e0));
            int4 c = pd[0], g = pd[1];
            d[0] = c.x; d[1] = c.z; d[2] = g.x; d[3] = g.z;
        } else {
            int4 a = *(const int4*)(ei + (size_t)e0);
            s[0] = a.x; s[1] = a.y; s[2] = a.z; s[3] = a.w;
            int4 c = *(const int4*)(ei + (size_t)N_EDGES + e0);
            d[0] = c.x; d[1] = c.y; d[2] = c.z; d[3] = c.w;
        }
#pragma unroll
        for (int j = 0; j < 4; ++j) {
            if ((unsigned)d[j] < N_NODES) {
                int r = atomicAdd(&deg[d[j]], 1);
                if ((unsigned)s[j] < N_NODES) {
                    if (r < SLOTS) {
                        csrF[(size_t)d[j] * SLOTS + r] = s[j];
                    } else {
                        int o = atomicAdd(novf, 1);
                        if (o < OVCAP) ov[o] = make_int2(d[j], s[j]);
                    }
                }
            }
        }
        return;
    }

    // -------- gemm1 MFMA tile --------
    int tile = blk - blk / 3 - 1;                       // 0..6249, exact bijection
    int isbf = flags[1];
    if (isbf) {
        const uint4* src = (const uint4*)W1p;
        uint4*       dst = (uint4*)w1s;
#pragma unroll
        for (int k = 0; k < 4; ++k) dst[tid + k * 256] = src[tid + k * 256];
        const short* xp = (const short*)x + (size_t)tile * 16 * F_IN;
        int r = tid >> 4, c = tid & 15;
        *(bf16x8*)(xs + r * XPAD + c * 8) = *(const bf16x8*)(xp + tid * 8);
    }
    __syncthreads();

    int wave = tid >> 6, lane = tid & 63;
    int col = lane & 15, quad = lane >> 4;
    int fg = wave;

    if (isbf) {
        bf16x8 afr[4];
#pragma unroll
        for (int kc = 0; kc < 4; ++kc)
            afr[kc] = *(const bf16x8*)(xs + col * XPAD + kc * 32 + quad * 8);
        f32x4 acc;
#pragma unroll
        for (int r = 0; r < 4; ++r) acc[r] = 0.f;
#pragma unroll
        for (int kc = 0; kc < 4; ++kc) {
            bf16x8 bfr = *(const bf16x8*)(w1s + (((kc * 4 + fg) * 64 + lane) * 8));
            acc = __builtin_amdgcn_mfma_f32_16x16x32_bf16(afr[kc], bfr, acc, 0, 0, 0);
        }
#pragma unroll
        for (int r = 0; r < 4; ++r)
            h1[(size_t)(tile * 16 + quad * 4 + r) * H1F + fg * 16 + col] = f2us(acc[r]);
    } else {
        const float* wfp = (const float*)W1;
        for (int i = 0; i < 4; ++i) {
            int n = tile * 16 + wave * 4 + i;
            const float2* xr = (const float2*)((const float*)x + (size_t)n * F_IN);
            float2 my = xr[lane];
            float acc = 0.f;
#pragma unroll 16
            for (int k = 0; k < 64; ++k) {
                float x0 = __shfl(my.x, k, 64);
                float x1 = __shfl(my.y, k, 64);
                acc += x0 * wfp[(2 * k) * H1F + lane];
                acc += x1 * wfp[(2 * k + 1) * H1F + lane];
            }
            h1[(size_t)n * H1F + lane] = f2us(acc);
        }
    }
}

// ---------------- fused agg1 + bias/ReLU + GEMM2 -> h2(bf16) ; wave per node ----------------
__global__ void k_agg1gemm2(const unsigned short* __restrict__ h1,
                            const int* __restrict__ deg,
                            const int* __restrict__ csrF,
                            const int* __restrict__ novf, const int2* __restrict__ ov,
                            const void* __restrict__ b1, const void* __restrict__ W2,
                            unsigned short* __restrict__ h2, const int* __restrict__ flags) {
    int n    = (blockIdx.x * blockDim.x + threadIdx.x) >> 6;
    int lane = threadIdx.x & 63;
    if (n >= N_NODES) return;
    int dg  = deg[n];
    int end = dg < SLOTS ? dg : SLOTS;
    const int* row = csrF + (size_t)n * SLOTS;
    float dn  = dinvf(dg);
    float acc = dn * us2f(h1[(size_t)n * H1F + lane]);  // self-loop
    int e = 0;
    for (; e + 3 < end; e += 4) {                       // 4-deep MLP
        int s0 = row[e], s1 = row[e + 1], s2 = row[e + 2], s3 = row[e + 3];
        float w0 = dinvf(deg[s0]), w1 = dinvf(deg[s1]);
        float w2 = dinvf(deg[s2]), w3 = dinvf(deg[s3]);
        unsigned short v0 = h1[(size_t)s0 * H1F + lane];
        unsigned short v1 = h1[(size_t)s1 * H1F + lane];
        unsigned short v2 = h1[(size_t)s2 * H1F + lane];
        unsigned short v3 = h1[(size_t)s3 * H1F + lane];
        acc += w0 * us2f(v0) + w1 * us2f(v1) + w2 * us2f(v2) + w3 * us2f(v3);
    }
    for (; e < end; ++e) {
        int s = row[e];
        acc += dinvf(deg[s]) * us2f(h1[(size_t)s * H1F + lane]);
    }
    int nov = *novf; nov = nov < OVCAP ? nov : OVCAP;   // overflow replay (normally 0)
    for (int i = 0; i < nov; ++i) {
        int2 p = ov[i];
        if (p.x == n) acc += dinvf(deg[p.y]) * us2f(h1[(size_t)p.y * H1F + lane]);
    }
    acc *= dn;                                          // agg1[n][lane]
    int isbf = flags[1];
    float bv = isbf ? b2f(((const __hip_bfloat16*)b1)[lane]) : ((const float*)b1)[lane];
    float v  = fmaxf(acc + bv, 0.f);                    // relu(agg1 + b1)
    int f = lane & 31, h = lane >> 5;
    float part = 0.f;
    if (isbf) {
        const __hip_bfloat16* w = (const __hip_bfloat16*)W2;
#pragma unroll
        for (int j = 0; j < 32; ++j) {
            int k = h * 32 + j;
            part += __shfl(v, k, 64) * b2f(w[k * H2F + f]);
        }
    } else {
        const float* w = (const float*)W2;
#pragma unroll
        for (int j = 0; j < 32; ++j) {
            int k = h * 32 + j;
            part += __shfl(v, k, 64) * w[k * H2F + f];
        }
    }
    part += __shfl(part, lane ^ 32, 64);                // combine halves
    if (h == 0) h2[(size_t)n * H2F + f] = f2us(part);
}

// ---------------- fused agg2 + final MLP -> out ; half-wave per node ----------------
__global__ void GCN_51737176048479_kernel(const unsigned short* __restrict__ h2,
                                          const int* __restrict__ deg,
                                          const int* __restrict__ csrF,
                                          const int* __restrict__ novf,
                                          const int2* __restrict__ ov,
                                          const void* __restrict__ b2v,
                                          const void* __restrict__ Wf,
                                          const void* __restrict__ bfv,
                                          const void* __restrict__ Wo,
                                          const void* __restrict__ bov,
                                          void* __restrict__ out,
                                          const int* __restrict__ flags) {
    int tid = blockIdx.x * blockDim.x + threadIdx.x;
    int n   = tid >> 5;
    int f   = threadIdx.x & 31;
    if (n >= N_NODES) return;
    int isbf = flags[1];
    int dg  = deg[n];
    int end = dg < SLOTS ? dg : SLOTS;
    const int* row = csrF + (size_t)n * SLOTS;
    float dn = dinvf(dg);
    float ar = dn * us2f(h2[(size_t)n * H2F + f]);
    int e = 0;
    for (; e + 3 < end; e += 4) {
        int s0 = row[e], s1 = row[e + 1], s2 = row[e + 2], s3 = row[e + 3];
        float w0 = dinvf(deg[s0]), w1 = dinvf(deg[s1]);
        float w2 = dinvf(deg[s2]), w3 = dinvf(deg[s3]);
        unsigned short v0 = h2[(size_t)s0 * H2F + f];
        unsigned short v1 = h2[(size_t)s1 * H2F + f];
        unsigned short v2 = h2[(size_t)s2 * H2F + f];
        unsigned short v3 = h2[(size_t)s3 * H2F + f];
        ar += w0 * us2f(v0) + w1 * us2f(v1) + w2 * us2f(v2) + w3 * us2f(v3);
    }
    for (; e < end; ++e) {
        int s = row[e];
        ar += dinvf(deg[s]) * us2f(h2[(size_t)s * H2F + f]);
    }
    int nov = *novf; nov = nov < OVCAP ? nov : OVCAP;
    for (int i = 0; i < nov; ++i) {
        int2 p = ov[i];
        if (p.x == n) ar += dinvf(deg[p.y]) * us2f(h2[(size_t)p.y * H2F + f]);
    }
    ar = ar * dn + ld(b2v, f, isbf);                    // conv2 out (no relu)
    float acc1 = 0.f;
#pragma unroll
    for (int k = 0; k < H2F; ++k)
        acc1 += __shfl(ar, k, 32) * ld(Wf, (size_t)k * H2F + f, isbf);
    float u = fmaxf(acc1 + ld(bfv, f, isbf), 0.f);
    float acc2 = 0.f;
#pragma unroll
    for (int k = 0; k < H2F; ++k)
        acc2 += __shfl(u, k, 32) * ld(Wo, (size_t)k * NCLS + f, isbf);
    float r = acc2 + ld(bov, f, isbf);
    size_t oi = (size_t)n * NCLS + f;
    if (isbf) ((__hip_bfloat16*)out)[oi] = __float2bfloat16(r);
    else      ((float*)out)[oi] = r;
}

extern "C" void kernel_launch(void* const* d_in, const int* in_sizes, int n_in,
                              void* d_out, int out_size, void* d_ws, size_t ws_size,
                              hipStream_t stream) {
    const void* x  = d_in[0];
    const int*  ei = (const int*)d_in[1];
    const void* W1 = d_in[2];
    const void* b1 = d_in[3];
    const void* W2 = d_in[4];
    const void* b2 = d_in[5];
    const void* Wf = d_in[6];
    const void* bf = d_in[7];
    const void* Wo = d_in[8];
    const void* bo = d_in[9];

    // workspace (peak ~54 MB):
    //  deg @0 (400000B) | novf @400000 (4B) | flags @512K | ov @520K (512KB)
    //  W1p @1.5M (16K) | csrF @2M (32MB) | h1 @35M (12.8MB bf16) | h2 @48M (6.4MB bf16)
    char* ws = (char*)d_ws;
    int*            deg   = (int*)  (ws + 0);
    int*            novf  = (int*)  (ws + 400000);
    int*            flags = (int*)  (ws + (512u << 10));
    int2*           ov    = (int2*) (ws + (520u << 10));
    unsigned short* W1p   = (unsigned short*)(ws + (1536u << 10));
    int*            csrF  = (int*)  (ws + (2u  << 20));
    unsigned short* h1    = (unsigned short*)(ws + (35u << 20));
    unsigned short* h2    = (unsigned short*)(ws + (48u << 20));

    const int B = 256;

    k_detect<<<1, 64, 0, stream>>>(x, ei, flags);
    hipMemsetAsync(deg, 0, 400000 + 4, stream);         // deg + novf
    k_packW1<<<(F_IN * H1F + B - 1) / B, B, 0, stream>>>((const unsigned short*)W1, W1p);

    // fused gemm1 + histogram + direct fixed-slot CSR scatter
    k_front<<<NTILES + NCNT, B, 0, stream>>>(x, W1, W1p, ei, deg, csrF, novf, ov,
                                             h1, flags);

    k_agg1gemm2<<<(N_NODES * 64 + B - 1) / B, B, 0, stream>>>(h1, deg, csrF, novf, ov,
                                                              b1, W2, h2, flags);
    GCN_51737176048479_kernel<<<(N_NODES * 32 + B - 1) / B, B, 0, stream>>>(
        h2, deg, csrF, novf, ov, b2, Wf, bf, Wo, bo, d_out, flags);
}